// Round 5
// baseline (273.817 us; speedup 1.0000x reference)
//
#include <hip/hip_runtime.h>
#include <math.h>

// Problem: N=8192, D=4096
//   inputs  (N, 2D) f32: mean = [:, :D], var = [:, D:]
//   targets (N, D)  f32
//   out = sum((mean - targets)^2 / var) + log(sum(var))   (scalar f32)
// Memory-bound: 384 MB read -> 1 float.  HBM roofline ~61 us; LLC retention
// across replays can take it lower.
//
// R5: R4 minus nontemporal loads (nt loads bypass cache path -> 760 GB/s,
//     263 us — reverted). Fused single launch + atomic finalize kept.

constexpr int N = 8192;
constexpr int D = 4096;
constexpr int BLOCKS = 2048;   // 256 CUs * 8 blocks/CU, exactly 1 dispatch round
constexpr int THREADS = 256;

typedef float f32x4 __attribute__((ext_vector_type(4)));

__global__ __launch_bounds__(THREADS, 8) void loss_fused_kernel(
    const float* __restrict__ inputs,
    const float* __restrict__ targets,
    float* __restrict__ ws,      // ws[0]=s1, ws[1]=s2, ws[3]=arrival counter
    float* __restrict__ out)
{
    constexpr unsigned NTHREAD = (unsigned)BLOCKS * THREADS;       // 524,288
    // total float4 triples = N*D/4 = 8,388,608 -> exactly 16 iters/thread

    float s1 = 0.0f;  // sum diff^2 / var
    float s2 = 0.0f;  // sum var

    unsigned i = blockIdx.x * (unsigned)THREADS + threadIdx.x;
    #pragma unroll 2
    for (int it = 0; it < 16; ++it, i += NTHREAD) {
        const unsigned row  = i >> 10;           // D/4 = 1024 float4 per row
        const unsigned col4 = (i & 1023u) << 2;  // column in floats

        const f32x4 m = *(const f32x4*)(inputs + (size_t)row * 8192u + col4);
        const f32x4 v = *(const f32x4*)(inputs + (size_t)row * 8192u + 4096u + col4);
        const f32x4 t = *(const f32x4*)(targets + (size_t)i * 4u);

        const float d0 = m.x - t.x;
        const float d1 = m.y - t.y;
        const float d2 = m.z - t.z;
        const float d3 = m.w - t.w;

        s1 += d0 * d0 * __builtin_amdgcn_rcpf(v.x);
        s1 += d1 * d1 * __builtin_amdgcn_rcpf(v.y);
        s1 += d2 * d2 * __builtin_amdgcn_rcpf(v.z);
        s1 += d3 * d3 * __builtin_amdgcn_rcpf(v.w);
        s2 += (v.x + v.y) + (v.z + v.w);
    }

    // wave (64-lane) shuffle reduction
    #pragma unroll
    for (int off = 32; off > 0; off >>= 1) {
        s1 += __shfl_down(s1, off, 64);
        s2 += __shfl_down(s2, off, 64);
    }

    __shared__ float l1[THREADS / 64];
    __shared__ float l2[THREADS / 64];
    const int wave = threadIdx.x >> 6;
    const int lane = threadIdx.x & 63;
    if (lane == 0) { l1[wave] = s1; l2[wave] = s2; }
    __syncthreads();

    if (threadIdx.x == 0) {
        const float a = (l1[0] + l1[1]) + (l1[2] + l1[3]);
        const float b = (l2[0] + l2[1]) + (l2[2] + l2[3]);
        // device-scope float atomics (order jitter ~ulp level, threshold 2.3e6)
        atomicAdd(&ws[0], a);
        atomicAdd(&ws[1], b);
        __threadfence();
        const unsigned old = __hip_atomic_fetch_add(
            (unsigned*)&ws[3], 1u, __ATOMIC_ACQ_REL, __HIP_MEMORY_SCOPE_AGENT);
        if (old == (unsigned)BLOCKS - 1u) {
            // last block to arrive: all atomicAdds are complete & visible
            const float fs1 = __hip_atomic_load(&ws[0], __ATOMIC_RELAXED,
                                                __HIP_MEMORY_SCOPE_AGENT);
            const float fs2 = __hip_atomic_load(&ws[1], __ATOMIC_RELAXED,
                                                __HIP_MEMORY_SCOPE_AGENT);
            out[0] = fs1 + logf(fs2);
        }
    }
}

extern "C" void kernel_launch(void* const* d_in, const int* in_sizes, int n_in,
                              void* d_out, int out_size, void* d_ws, size_t ws_size,
                              hipStream_t stream) {
    const float* inputs  = (const float*)d_in[0];
    const float* targets = (const float*)d_in[1];
    float* out = (float*)d_out;
    float* ws  = (float*)d_ws;

    // reset accumulators + arrival counter (16 bytes); graph-capturable
    (void)hipMemsetAsync(ws, 0, 16, stream);
    loss_fused_kernel<<<BLOCKS, THREADS, 0, stream>>>(inputs, targets, ws, out);
}

// Round 6
// 77.286 us; speedup vs baseline: 3.5429x; 3.5429x over previous
//
#include <hip/hip_runtime.h>
#include <math.h>

// Problem: N=8192, D=4096
//   inputs  (N, 2D) f32: mean = [:, :D], var = [:, D:]
//   targets (N, D)  f32
//   out = sum((mean - targets)^2 / var) + log(sum(var))   (scalar f32)
// Memory-bound: 384 MB read -> 1 float.  HBM roofline ~61 us @ 6.3 TB/s.
//
// R6: REVERT the fused atomic-finalize (R4/R5: threadfence+acq_rel atomics
//     force per-block L2 writeback/invalidate on non-coherent-XCD hardware ->
//     263-274 us). Back to the proven two-kernel reduction (R1: 78.6 us),
//     now with unroll 8 and no min-waves VGPR clamp for deeper load pipeline.

constexpr int N = 8192;
constexpr int D = 4096;
constexpr int BLOCKS = 2048;   // 256 CUs * 8 blocks/CU
constexpr int THREADS = 256;

typedef float f32x4 __attribute__((ext_vector_type(4)));

__global__ __launch_bounds__(THREADS) void loss_partial_kernel(
    const float* __restrict__ inputs,
    const float* __restrict__ targets,
    float* __restrict__ partials)   // [2 * BLOCKS]: s1 then s2
{
    constexpr unsigned NTHREAD = (unsigned)BLOCKS * THREADS;  // 524,288
    // total float4 triples = N*D/4 = 8,388,608 -> exactly 16 iters/thread

    float s1 = 0.0f;  // sum diff^2 / var
    float s2 = 0.0f;  // sum var

    unsigned i = blockIdx.x * (unsigned)THREADS + threadIdx.x;
    #pragma unroll 8
    for (int it = 0; it < 16; ++it, i += NTHREAD) {
        const unsigned row  = i >> 10;           // D/4 = 1024 float4 per row
        const unsigned col4 = (i & 1023u) << 2;  // column in floats

        const f32x4 m = *(const f32x4*)(inputs + (size_t)row * 8192u + col4);
        const f32x4 v = *(const f32x4*)(inputs + (size_t)row * 8192u + 4096u + col4);
        const f32x4 t = *(const f32x4*)(targets + (size_t)i * 4u);

        const float d0 = m.x - t.x;
        const float d1 = m.y - t.y;
        const float d2 = m.z - t.z;
        const float d3 = m.w - t.w;

        s1 += d0 * d0 * __builtin_amdgcn_rcpf(v.x);
        s1 += d1 * d1 * __builtin_amdgcn_rcpf(v.y);
        s1 += d2 * d2 * __builtin_amdgcn_rcpf(v.z);
        s1 += d3 * d3 * __builtin_amdgcn_rcpf(v.w);
        s2 += (v.x + v.y) + (v.z + v.w);
    }

    // wave (64-lane) shuffle reduction
    #pragma unroll
    for (int off = 32; off > 0; off >>= 1) {
        s1 += __shfl_down(s1, off, 64);
        s2 += __shfl_down(s2, off, 64);
    }

    __shared__ float l1[THREADS / 64];
    __shared__ float l2[THREADS / 64];
    const int wave = threadIdx.x >> 6;
    const int lane = threadIdx.x & 63;
    if (lane == 0) { l1[wave] = s1; l2[wave] = s2; }
    __syncthreads();

    if (threadIdx.x == 0) {
        const float a = (l1[0] + l1[1]) + (l1[2] + l1[3]);
        const float b = (l2[0] + l2[1]) + (l2[2] + l2[3]);
        partials[blockIdx.x]          = a;
        partials[BLOCKS + blockIdx.x] = b;
    }
}

__global__ __launch_bounds__(256) void loss_final_kernel(
    const float* __restrict__ partials,
    float* __restrict__ out)
{
    double s1 = 0.0, s2 = 0.0;
    for (int i = threadIdx.x; i < BLOCKS; i += 256) {
        s1 += (double)partials[i];
        s2 += (double)partials[BLOCKS + i];
    }

    #pragma unroll
    for (int off = 32; off > 0; off >>= 1) {
        s1 += __shfl_down(s1, off, 64);
        s2 += __shfl_down(s2, off, 64);
    }

    __shared__ double l1[4];
    __shared__ double l2[4];
    const int wave = threadIdx.x >> 6;
    const int lane = threadIdx.x & 63;
    if (lane == 0) { l1[wave] = s1; l2[wave] = s2; }
    __syncthreads();

    if (threadIdx.x == 0) {
        const double a = (l1[0] + l1[1]) + (l1[2] + l1[3]);
        const double b = (l2[0] + l2[1]) + (l2[2] + l2[3]);
        out[0] = (float)(a + log(b));
    }
}

extern "C" void kernel_launch(void* const* d_in, const int* in_sizes, int n_in,
                              void* d_out, int out_size, void* d_ws, size_t ws_size,
                              hipStream_t stream) {
    const float* inputs  = (const float*)d_in[0];
    const float* targets = (const float*)d_in[1];
    float* out      = (float*)d_out;
    float* partials = (float*)d_ws;   // 2 * BLOCKS * 4 = 16 KB

    loss_partial_kernel<<<BLOCKS, THREADS, 0, stream>>>(inputs, targets, partials);
    loss_final_kernel<<<1, 256, 0, stream>>>(partials, out);
}